// Round 15
// baseline (198.479 us; speedup 1.0000x reference)
//
#include <hip/hip_runtime.h>
#include <hip/hip_bf16.h>

typedef unsigned short u16;
typedef __attribute__((ext_vector_type(8))) short bf16x8;
typedef __attribute__((ext_vector_type(4))) float f32x4;

#define MFMA16(a, b, c) __builtin_amdgcn_mfma_f32_16x16x32_bf16((a), (b), (c), 0, 0, 0)

#define NB 64
#define ND 1024
#define NQ 128
#define NE 300
#define NH 256
#define KP 320
#define QETN 304
#define DOC_W 624

static __device__ __forceinline__ u16 f2bf(float f) {
  union { __bf16 h; u16 u; } c; c.h = (__bf16)f; return c.u;
}

static __device__ __forceinline__ bf16x8 pack8(float4 f0, float4 f1) {
  union { bf16x8 v; u16 u[8]; } r;
  r.u[0] = f2bf(f0.x); r.u[1] = f2bf(f0.y); r.u[2] = f2bf(f0.z); r.u[3] = f2bf(f0.w);
  r.u[4] = f2bf(f1.x); r.u[5] = f2bf(f1.y); r.u[6] = f2bf(f1.z); r.u[7] = f2bf(f1.w);
  return r.v;
}

static __device__ __forceinline__ bf16x8 cvt8(const float* p) {
  return pack8(*(const float4*)p, *(const float4*)(p + 4));
}

// ---- k_aux: [0,320) Wt transpose; [320,2720) query embed; [2720,4256) extras ----
__global__ void k_aux(const float* __restrict__ w, u16* __restrict__ wt,
                      const int* __restrict__ qtok, const float* __restrict__ table,
                      float* __restrict__ q_out,
                      const int* __restrict__ ner, const int* __restrict__ pos,
                      const float* __restrict__ fea,
                      const float* __restrict__ ner_emb, const float* __restrict__ pos_emb,
                      float* __restrict__ doc_out) {
  int bx = blockIdx.x;
  if (bx < 320) {
    int idx = bx * 256 + threadIdx.x;  // exactly NH*KP = 81920
    int n = idx / KP, k = idx % KP;
    wt[idx] = (k < NE) ? f2bf(w[k * NH + n]) : (u16)0;
  } else if (bx < 2720) {
    int idx = (bx - 320) * 256 + threadIdx.x;  // exactly 8192*75
    int row = idx / 75, j = idx % 75;
    int k = j * 4;
    float4 v = {0.f, 0.f, 0.f, 0.f};
    int t = qtok[row];
    if (t != 0) v = *(const float4*)(table + (long)t * NE + k);
    *(float4*)(q_out + (long)row * NE + k) = v;
  } else {
    int idx = (bx - 2720) * 256 + threadIdx.x;  // exactly 65536*6
    int row = idx / 6, c0 = (idx % 6) * 4;
    float4 v;
    float* vp = (float*)&v;
#pragma unroll
    for (int u = 0; u < 4; ++u) {
      int c = c0 + u;
      float x;
      if (c < 8)       { int t = ner[row]; x = t ? ner_emb[t * 8 + c] : 0.f; }
      else if (c < 20) { int t = pos[row]; x = t ? pos_emb[t * 12 + (c - 8)] : 0.f; }
      else             { x = fea[(long)row * 4 + (c - 20)]; }
      vp[u] = x;
    }
    *(float4*)(doc_out + (long)row * DOC_W + 600 + c0) = v;
  }
}

// ---- q-side combo: blocks [0,128) = q_proj GEMM; [128,256) = qeT transpose ----
__launch_bounds__(256)
__global__ void k_qside(const float* __restrict__ qo, const u16* __restrict__ Wt,
                        const float* __restrict__ bias,
                        u16* __restrict__ qP, u16* __restrict__ qet) {
  __shared__ u16 T[64][314];
  int tid = threadIdx.x;
  if (blockIdx.x < 128) {
    int l = tid & 63, w = tid >> 6;
    int lr = l & 15, lg = l >> 4;
    int bm = blockIdx.x * 64 + (w & 1) * 32;
    int bn = (w >> 1) * 128;
    f32x4 acc[2][8] = {};
    const float* xp0 = qo + (long)(bm + lr) * NE + 8 * lg;
    const float* xp1 = xp0 + 16 * NE;
    const u16* wp = Wt + (long)(bn + lr) * KP + 8 * lg;
#pragma unroll 2
    for (int ks = 0; ks < KP; ks += 32) {
      bf16x8 a0 = cvt8(xp0 + ks);  // rows*300 stride: k-tail junk x zero Wt rows -> 0
      bf16x8 a1 = cvt8(xp1 + ks);
#pragma unroll
      for (int nt = 0; nt < 8; ++nt) {
        bf16x8 b0 = *(const bf16x8*)(wp + (long)nt * 16 * KP + ks);
        acc[0][nt] = MFMA16(a0, b0, acc[0][nt]);
        acc[1][nt] = MFMA16(a1, b0, acc[1][nt]);
      }
    }
#pragma unroll
    for (int nt = 0; nt < 8; ++nt) {
      int col = bn + nt * 16 + lr;
      float bv = bias[col];
#pragma unroll
      for (int mt = 0; mt < 2; ++mt)
#pragma unroll
        for (int r = 0; r < 4; ++r) {
          int row = bm + mt * 16 + 4 * lg + r;
          float v = acc[mt][nt][r] + bv;
          v = v > 0.f ? v : 0.f;
          qP[(long)row * NH + col] = f2bf(v);
        }
    }
  } else {
    int bx = blockIdx.x - 128;
    int b = bx >> 1, k0 = (bx & 1) * 64;
    const float* src = qo + ((long)b * NQ + k0) * NE;
    for (int i = tid; i < 64 * 75; i += 256) {
      int row = i / 75, j = (i % 75) * 4;
      float4 f = *(const float4*)(src + (long)row * NE + j);
      T[row][j]     = f2bf(f.x); T[row][j + 1] = f2bf(f.y);
      T[row][j + 2] = f2bf(f.z); T[row][j + 3] = f2bf(f.w);
    }
    __syncthreads();
    u16* dst = qet + (long)b * QETN * NQ + k0;
    for (int i = tid; i < QETN * 16; i += 256) {
      int n = i / 16, kq = (i % 16) * 4;
      u16 v[4] = {0, 0, 0, 0};
      if (n < NE) {
        v[0] = T[kq][n]; v[1] = T[kq + 1][n]; v[2] = T[kq + 2][n]; v[3] = T[kq + 3][n];
      }
      *(uint2*)(dst + (long)n * NQ + kq) = *(const uint2*)v;
    }
  }
}

// ---- fused: doc embed gather + d_proj (LDS) -> scores -> softmax -> prealign ----
// 64-row block, 4 waves. Stage 1: M=64 x N=64 per wave -- SAME 8-gather-loads/
// K-step ILP as R9's best, but block LDS halves to 33.8 KB -> 4 blocks/CU =
// 16 waves/CU (2x R9's). Col-wave duplication (x4 gather) is L2-served (R6/R9/
// R14: dup never surfaced in FETCH). Stages 2-4: M=16/wave. 2 barriers.
__launch_bounds__(256, 4)
__global__ void k_fused(const int* __restrict__ dtok, const float* __restrict__ emb,
                        float* doc_out, const u16* __restrict__ Wt,
                        const float* __restrict__ bias,
                        const u16* __restrict__ qP, const u16* __restrict__ qeT) {
  __shared__ __align__(16) u16 dp[64][264];
  u16 (*p_lds)[136] = (u16 (*)[136]) & dp[0][0];
  // XCD swizzle: bijective over 1024 = 8 xcd x 8 b x 16 chunks; all 16 chunks
  // of a batch b land on one XCD (consecutive bids round-robin XCDs).
  int bid = blockIdx.x;
  int xcd = bid & 7, j = bid >> 3;
  int b = xcd * 8 + (j >> 4);
  int chunk = j & 15;
  int l = threadIdx.x & 63, w = threadIdx.x >> 6;
  int lr = l & 15, lg = l >> 4;
  long blkrow = (long)b * ND + chunk * 64;
  int c0 = 8 * lg;

  // stage 1: gather + d_proj. Every wave: all 64 rows x its 64-col panel.
  {
    int ncol0 = w * 64;
    bool wr = (w == 0);  // wave 0 writes doc_e cols 0:300 (f32) once per row
    const float* arow[4];
    float* drow[4];
#pragma unroll
    for (int mt = 0; mt < 4; ++mt) {
      long r = blkrow + mt * 16 + lr;
      arow[mt] = emb + (long)dtok[r] * NE;
      drow[mt] = doc_out + r * DOC_W;
    }
    const u16* wp = Wt + (long)(ncol0 + lr) * KP + c0;
    f32x4 acc[4][4] = {};
#pragma unroll 3
    for (int ks = 0; ks < 288; ks += 32) {  // cols ks+c0 in [0,288): all in-table
      bf16x8 a[4];
#pragma unroll
      for (int mt = 0; mt < 4; ++mt) {
        int col = ks + c0;
        float4 f0 = *(const float4*)(arow[mt] + col);
        float4 f1 = *(const float4*)(arow[mt] + col + 4);
        if (wr) {
          *(float4*)(drow[mt] + col) = f0;
          *(float4*)(drow[mt] + col + 4) = f1;
        }
        a[mt] = pack8(f0, f1);
      }
#pragma unroll
      for (int nt = 0; nt < 4; ++nt) {
        bf16x8 bb = *(const bf16x8*)(wp + nt * 16 * KP + ks);
#pragma unroll
        for (int mt = 0; mt < 4; ++mt) acc[mt][nt] = MFMA16(a[mt], bb, acc[mt][nt]);
      }
    }
    {  // K-tail ks=288: cols 288..319; mask loads past col 300 (table-end OOB)
      const int ks = 288;
      int col = ks + c0;
      float4 z = {0.f, 0.f, 0.f, 0.f};
      bf16x8 a[4];
#pragma unroll
      for (int mt = 0; mt < 4; ++mt) {
        float4 f0 = (col + 4 <= NE) ? *(const float4*)(arow[mt] + col) : z;
        float4 f1 = (col + 8 <= NE) ? *(const float4*)(arow[mt] + col + 4) : z;
        if (wr) {
          if (col + 4 <= NE) *(float4*)(drow[mt] + col) = f0;
          if (col + 8 <= NE) *(float4*)(drow[mt] + col + 4) = f1;
        }
        a[mt] = pack8(f0, f1);
      }
#pragma unroll
      for (int nt = 0; nt < 4; ++nt) {
        bf16x8 bb = *(const bf16x8*)(wp + nt * 16 * KP + ks);
#pragma unroll
        for (int mt = 0; mt < 4; ++mt) acc[mt][nt] = MFMA16(a[mt], bb, acc[mt][nt]);
      }
    }
#pragma unroll
    for (int nt = 0; nt < 4; ++nt) {
      int col = ncol0 + nt * 16 + lr;
      float bv = bias[col];
#pragma unroll
      for (int mt = 0; mt < 4; ++mt)
#pragma unroll
        for (int r = 0; r < 4; ++r) {
          float v = acc[mt][nt][r] + bv;
          dp[mt * 16 + 4 * lg + r][col] = f2bf(v > 0.f ? v : 0.f);
        }
    }
  }
  __syncthreads();  // dp cols are cross-wave from here on

  // stage 2: scores S[16][128] per wave (rows w*16..), K = 256
  f32x4 s[8] = {};
  {
    const u16* qpp = qP + ((long)b * NQ + lr) * NH + 8 * lg;
#pragma unroll
    for (int ks = 0; ks < NH; ks += 32) {
      bf16x8 a0 = *(const bf16x8*)&dp[w * 16 + lr][ks + 8 * lg];
#pragma unroll
      for (int nt = 0; nt < 8; ++nt) {
        bf16x8 bb = *(const bf16x8*)(qpp + (long)nt * 16 * NH + ks);
        s[nt] = MFMA16(a0, bb, s[nt]);
      }
    }
  }
  __syncthreads();  // all dp reads complete before p_lds overlay is written

  // stage 3: softmax over q, write P bf16 to p_lds (own rows only)
  {
    f32x4 mx;
#pragma unroll
    for (int r = 0; r < 4; ++r) {
      float m = s[0][r];
#pragma unroll
      for (int nt = 1; nt < 8; ++nt) m = fmaxf(m, s[nt][r]);
      mx[r] = m;
    }
#pragma unroll
    for (int d = 1; d < 16; d <<= 1)
#pragma unroll
      for (int r = 0; r < 4; ++r) mx[r] = fmaxf(mx[r], __shfl_xor(mx[r], d));
    f32x4 sum = {};
#pragma unroll
    for (int nt = 0; nt < 8; ++nt)
#pragma unroll
      for (int r = 0; r < 4; ++r) {
        float p = __expf(s[nt][r] - mx[r]);
        s[nt][r] = p;
        sum[r] += p;
      }
#pragma unroll
    for (int d = 1; d < 16; d <<= 1)
#pragma unroll
      for (int r = 0; r < 4; ++r) sum[r] += __shfl_xor(sum[r], d);
    f32x4 inv;
#pragma unroll
    for (int r = 0; r < 4; ++r) inv[r] = 1.0f / sum[r];
#pragma unroll
    for (int nt = 0; nt < 8; ++nt)
#pragma unroll
      for (int r = 0; r < 4; ++r)
        p_lds[w * 16 + 4 * lg + r][nt * 16 + lr] = f2bf(s[nt][r] * inv[r]);
  }
  // own-row reads in stage 4 -> no barrier

  // stage 4: prealign = P @ query_e[b] (K = 128) -> doc_out cols 300:600 f32
  const u16* qtp = qeT + (long)b * QETN * NQ;
  bf16x8 pa[4];  // invariant A-fragments hoisted out of the nt loop
#pragma unroll
  for (int ksi = 0; ksi < 4; ++ksi)
    pa[ksi] = *(const bf16x8*)&p_lds[w * 16 + lr][ksi * 32 + c0];
#pragma unroll 2
  for (int nt = 0; nt < 19; ++nt) {
    f32x4 acc0 = {};
#pragma unroll
    for (int ksi = 0; ksi < 4; ++ksi) {
      bf16x8 bb = *(const bf16x8*)(qtp + (long)(nt * 16 + lr) * NQ + ksi * 32 + c0);
      acc0 = MFMA16(pa[ksi], bb, acc0);
    }
    int col = nt * 16 + lr;
    if (col < NE) {
#pragma unroll
      for (int r = 0; r < 4; ++r)
        doc_out[(blkrow + w * 16 + 4 * lg + r) * DOC_W + 300 + col] = acc0[r];
    }
  }
}

extern "C" void kernel_launch(void* const* d_in, const int* in_sizes, int n_in,
                              void* d_out, int out_size, void* d_ws, size_t ws_size,
                              hipStream_t stream) {
  // Size-based dispatch (R3/R4: identical to dict order; kept for robustness).
  const int *query_tok = nullptr, *doc_tok = nullptr, *doc_pos = nullptr, *doc_ner = nullptr;
  const float *doc_fea = nullptr, *word_emb = nullptr, *proj_w = nullptr,
              *proj_b = nullptr, *pos_emb = nullptr, *ner_emb = nullptr;
  int n65536 = 0;
  for (int i = 0; i < n_in; ++i) {
    switch (in_sizes[i]) {
      case 15000000: word_emb  = (const float*)d_in[i]; break;  // 50000*300
      case 262144:   doc_fea   = (const float*)d_in[i]; break;  // 64*1024*4
      case 76800:    proj_w    = (const float*)d_in[i]; break;  // 300*256
      case 8192:     query_tok = (const int*)d_in[i];   break;  // 64*128
      case 256:      proj_b    = (const float*)d_in[i]; break;
      case 672:      pos_emb   = (const float*)d_in[i]; break;  // 56*12
      case 152:      ner_emb   = (const float*)d_in[i]; break;  // 19*8
      case 65536:                                               // 64*1024 ints
        if (n65536 == 0)      doc_tok = (const int*)d_in[i];
        else if (n65536 == 1) doc_pos = (const int*)d_in[i];
        else                  doc_ner = (const int*)d_in[i];
        ++n65536; break;
      default: break;
    }
  }

  float* out = (float*)d_out;
  float* q_out   = out;                         // [B*Q][300] f32
  float* doc_out = out + (size_t)NB * NQ * NE;  // [B*D][624] f32

  char* ws = (char*)d_ws;
  u16* Wt  = (u16*)ws; ws += (size_t)NH * KP * 2;        // 160 KB
  u16* qP  = (u16*)ws; ws += (size_t)NB * NQ * NH * 2;   // 4 MB
  u16* qeT = (u16*)ws; ws += (size_t)NB * QETN * NQ * 2; // 4.75 MB

  k_aux<<<dim3(4256), dim3(256), 0, stream>>>(
      proj_w, Wt, query_tok, word_emb, q_out,
      doc_ner, doc_pos, doc_fea, ner_emb, pos_emb, doc_out);
  k_qside<<<dim3(256), dim3(256), 0, stream>>>(q_out, Wt, proj_b, qP, qeT);
  k_fused<<<dim3(1024), dim3(256), 0, stream>>>(
      doc_tok, word_emb, doc_out, Wt, proj_b, qP, qeT);
}

// Round 17
// 120.642 us; speedup vs baseline: 1.6452x; 1.6452x over previous
//
#include <hip/hip_runtime.h>
#include <hip/hip_bf16.h>

typedef unsigned short u16;
typedef __attribute__((ext_vector_type(8))) short bf16x8;
typedef __attribute__((ext_vector_type(4))) float f32x4;

#define MFMA16(a, b, c) __builtin_amdgcn_mfma_f32_16x16x32_bf16((a), (b), (c), 0, 0, 0)

#define NB 64
#define ND 1024
#define NQ 128
#define NE 300
#define NH 256
#define KP 320
#define QETN 304
#define DOC_W 624

static __device__ __forceinline__ u16 f2bf(float f) {
  union { __bf16 h; u16 u; } c; c.h = (__bf16)f; return c.u;
}

static __device__ __forceinline__ bf16x8 pack8(float4 f0, float4 f1) {
  union { bf16x8 v; u16 u[8]; } r;
  r.u[0] = f2bf(f0.x); r.u[1] = f2bf(f0.y); r.u[2] = f2bf(f0.z); r.u[3] = f2bf(f0.w);
  r.u[4] = f2bf(f1.x); r.u[5] = f2bf(f1.y); r.u[6] = f2bf(f1.z); r.u[7] = f2bf(f1.w);
  return r.v;
}

// ---- k_pre (1024-thread blocks; one launch replaces k_aux + k_qside):
// [0,80)      Wt[n][k] = bf16(proj_w[k][n]) (zero k>=300)      -> ws
// [80,680)    query embed -> q_out (f32 output)
// [680,1064)  ner/pos/fea -> doc_out cols 600:624
// [1064,1192) qeT: gather word_emb + LDS transpose -> ws       (R10-verified)
// [1192,1320) qP:  gather-GEMM, per-block self-staged Wt slice -> ws
__global__ void k_pre(const float* __restrict__ w, u16* __restrict__ wt,
                      const int* __restrict__ qtok, const float* __restrict__ emb,
                      float* __restrict__ q_out, u16* __restrict__ qet,
                      const int* __restrict__ ner, const int* __restrict__ pos,
                      const float* __restrict__ fea,
                      const float* __restrict__ ner_emb, const float* __restrict__ pos_emb,
                      float* __restrict__ doc_out,
                      const float* __restrict__ bias, u16* __restrict__ qP) {
  __shared__ u16 T[64][322];  // stride 322: bank-stride 161%32==1 -> conflict-free
  int bx = blockIdx.x, tid = threadIdx.x;
  if (bx < 80) {
    int idx = bx * 1024 + tid;  // exactly NH*KP = 81920
    int n = idx / KP, k = idx % KP;
    wt[idx] = (k < NE) ? f2bf(w[k * NH + n]) : (u16)0;
  } else if (bx < 680) {
    int idx = (bx - 80) * 1024 + tid;  // exactly 8192*75
    int row = idx / 75, j = (idx % 75) * 4;
    float4 v = {0.f, 0.f, 0.f, 0.f};
    int t = qtok[row];
    if (t != 0) v = *(const float4*)(emb + (long)t * NE + j);
    *(float4*)(q_out + (long)row * NE + j) = v;
  } else if (bx < 1064) {
    int idx = (bx - 680) * 1024 + tid;  // exactly 65536*6
    int row = idx / 6, c0 = (idx % 6) * 4;
    float4 v;
    float* vp = (float*)&v;
#pragma unroll
    for (int u = 0; u < 4; ++u) {
      int c = c0 + u;
      float x;
      if (c < 8)       { int t = ner[row]; x = t ? ner_emb[t * 8 + c] : 0.f; }
      else if (c < 20) { int t = pos[row]; x = t ? pos_emb[t * 12 + (c - 8)] : 0.f; }
      else             { x = fea[(long)row * 4 + (c - 20)]; }
      vp[u] = x;
    }
    *(float4*)(doc_out + (long)row * DOC_W + 600 + c0) = v;
  } else if (bx < 1192) {
    // qeT[b][n][k] = bf16(query_e[b*128+k0+.. ][n]); n in [300,304) -> 0
    int bxx = bx - 1064;
    int b = bxx >> 1, k0 = (bxx & 1) * 64;
    for (int i = tid; i < 64 * 75; i += 1024) {
      int row = i / 75, j = (i % 75) * 4;
      int t = qtok[b * NQ + k0 + row];
      float4 f = {0.f, 0.f, 0.f, 0.f};
      if (t != 0) f = *(const float4*)(emb + (long)t * NE + j);
      T[row][j]     = f2bf(f.x); T[row][j + 1] = f2bf(f.y);
      T[row][j + 2] = f2bf(f.z); T[row][j + 3] = f2bf(f.w);
    }
    __syncthreads();
    u16* dst = qet + (long)b * QETN * NQ + k0;
    for (int i = tid; i < QETN * 16; i += 1024) {
      int n = i / 16, kq = (i % 16) * 4;
      u16 v[4] = {0, 0, 0, 0};
      if (n < NE) {
        v[0] = T[kq][n]; v[1] = T[kq + 1][n]; v[2] = T[kq + 2][n]; v[3] = T[kq + 3][n];
      }
      *(uint2*)(dst + (long)n * NQ + kq) = *(const uint2*)v;
    }
  } else {
    // qP: block = 256 q-rows x 64 cols; 16 waves, wave wv = rows [bm0,bm0+16).
    int bx2 = bx - 1192;              // [0,128)
    int rowg = bx2 >> 2, colg = bx2 & 3;
    int ncol0 = colg * 64;
    // stage Wt slice: T[n][k] = bf16(proj_w[k][ncol0+n]) for ALL k in [0,300)
    // (R16 bug: bound was 75*64 -> k only reached 74; rows 75..299 were garbage)
    for (int i = tid; i < 300 * 64; i += 1024) {
      int n = i & 63, k = i >> 6;
      T[n][k] = f2bf(w[k * NH + ncol0 + n]);
    }
    for (int i = tid; i < 64 * 22; i += 1024)
      T[i / 22][300 + (i % 22)] = 0;
    __syncthreads();
    int l = tid & 63, wv = tid >> 6;
    int lr = l & 15, lg = l >> 4, c0 = 8 * lg;
    int bm0 = rowg * 256 + wv * 16;
    const float* ar = emb + (long)qtok[bm0 + lr] * NE;  // tok 0 -> zero row of emb
    f32x4 acc[4] = {};
#pragma unroll 3
    for (int ks = 0; ks < 288; ks += 32) {  // cols <= 280+8 <= 288 < 300: unmasked
      bf16x8 a0 = pack8(*(const float4*)(ar + ks + c0), *(const float4*)(ar + ks + c0 + 4));
#pragma unroll
      for (int nt = 0; nt < 4; ++nt) {
        bf16x8 bb = *(const bf16x8*)&T[nt * 16 + lr][ks + c0];
        acc[nt] = MFMA16(a0, bb, acc[nt]);
      }
    }
    {  // tail ks=288: mask loads past col 300 (table-end OOB guard); T zero there
      const int ks = 288;
      int col = ks + c0;
      float4 z = {0.f, 0.f, 0.f, 0.f};
      float4 f0 = (col + 4 <= NE) ? *(const float4*)(ar + col) : z;
      float4 f1 = (col + 8 <= NE) ? *(const float4*)(ar + col + 4) : z;
      bf16x8 a0 = pack8(f0, f1);
#pragma unroll
      for (int nt = 0; nt < 4; ++nt) {
        bf16x8 bb = *(const bf16x8*)&T[nt * 16 + lr][ks + c0];
        acc[nt] = MFMA16(a0, bb, acc[nt]);
      }
    }
#pragma unroll
    for (int nt = 0; nt < 4; ++nt) {
      int col = ncol0 + nt * 16 + lr;
      float bv = bias[col];
#pragma unroll
      for (int r = 0; r < 4; ++r) {
        int row = bm0 + 4 * lg + r;
        float v = acc[nt][r] + bv;
        v = v > 0.f ? v : 0.f;
        qP[(long)row * NH + col] = f2bf(v);
      }
    }
  }
}

// ---- fused (R14 verbatim, best measured): doc embed gather + d_proj (LDS) ->
// scores -> softmax -> prealign. 128 rows/block, XCD swizzle. ----
__launch_bounds__(256, 2)
__global__ void k_fused(const int* __restrict__ dtok, const float* __restrict__ emb,
                        float* doc_out, const u16* __restrict__ Wt,
                        const float* __restrict__ bias,
                        const u16* __restrict__ qP, const u16* __restrict__ qeT) {
  __shared__ __align__(16) u16 dp[128][264];
  u16 (*p_lds)[136] = (u16 (*)[136]) & dp[0][0];
  int bid = blockIdx.x;
  int xcd = bid & 7, j = bid >> 3;
  int b = xcd * 8 + (j >> 3);
  int chunk = j & 7;
  int l = threadIdx.x & 63, w = threadIdx.x >> 6;
  int lr = l & 15, lg = l >> 4;
  long blkrow = (long)b * ND + chunk * 128;

  // stage 1: gather + d_proj tile -> dp. Wave w: rows (w&1)*64+[0,64), cols (w>>1)*128+[0,128)
  {
    int mrow0 = (w & 1) * 64;
    int ncol0 = (w >> 1) * 128;
    bool wr = (w >> 1) == 0;  // only col-wave 0 writes doc_out
    const float* arow[4];
    float* drow[4];
#pragma unroll
    for (int mt = 0; mt < 4; ++mt) {
      long r = blkrow + mrow0 + mt * 16 + lr;
      arow[mt] = emb + (long)dtok[r] * NE;
      drow[mt] = doc_out + r * DOC_W;
    }
    const u16* wp = Wt + (long)(ncol0 + lr) * KP + 8 * lg;
    f32x4 acc[4][8] = {};
    int c0 = 8 * lg;
#pragma unroll 3
    for (int ks = 0; ks < 288; ks += 32) {  // cols ks+c0 in [0,288): all in-table
      bf16x8 a[4];
#pragma unroll
      for (int mt = 0; mt < 4; ++mt) {
        int col = ks + c0;
        float4 f0 = *(const float4*)(arow[mt] + col);
        float4 f1 = *(const float4*)(arow[mt] + col + 4);
        if (wr) {
          *(float4*)(drow[mt] + col) = f0;
          *(float4*)(drow[mt] + col + 4) = f1;
        }
        a[mt] = pack8(f0, f1);
      }
#pragma unroll
      for (int nt = 0; nt < 8; ++nt) {
        bf16x8 bb = *(const bf16x8*)(wp + nt * 16 * KP + ks);
#pragma unroll
        for (int mt = 0; mt < 4; ++mt) acc[mt][nt] = MFMA16(a[mt], bb, acc[mt][nt]);
      }
    }
    {  // K-tail ks=288: cols 288..319; mask loads past col 300 (avoids OOB at table end)
      const int ks = 288;
      int col = ks + c0;
      float4 z = {0.f, 0.f, 0.f, 0.f};
      bf16x8 a[4];
#pragma unroll
      for (int mt = 0; mt < 4; ++mt) {
        float4 f0 = (col + 4 <= NE) ? *(const float4*)(arow[mt] + col) : z;
        float4 f1 = (col + 8 <= NE) ? *(const float4*)(arow[mt] + col + 4) : z;
        if (wr) {
          if (col + 4 <= NE) *(float4*)(drow[mt] + col) = f0;
          if (col + 8 <= NE) *(float4*)(drow[mt] + col + 4) = f1;
        }
        a[mt] = pack8(f0, f1);
      }
#pragma unroll
      for (int nt = 0; nt < 8; ++nt) {
        bf16x8 bb = *(const bf16x8*)(wp + nt * 16 * KP + ks);
#pragma unroll
        for (int mt = 0; mt < 4; ++mt) acc[mt][nt] = MFMA16(a[mt], bb, acc[mt][nt]);
      }
    }
#pragma unroll
    for (int nt = 0; nt < 8; ++nt) {
      int col = ncol0 + nt * 16 + lr;
      float bv = bias[col];
#pragma unroll
      for (int mt = 0; mt < 4; ++mt)
#pragma unroll
        for (int r = 0; r < 4; ++r) {
          float v = acc[mt][nt][r] + bv;
          dp[mrow0 + mt * 16 + 4 * lg + r][col] = f2bf(v > 0.f ? v : 0.f);
        }
    }
  }
  __syncthreads();  // dp rows are cross-wave from here on

  // stage 2: scores S[32][128] per wave (rows w*32..), K = 256
  f32x4 s[2][8] = {};
  {
    const u16* qpp = qP + ((long)b * NQ + lr) * NH + 8 * lg;
#pragma unroll
    for (int ks = 0; ks < NH; ks += 32) {
      bf16x8 a0 = *(const bf16x8*)&dp[w * 32 + lr][ks + 8 * lg];
      bf16x8 a1 = *(const bf16x8*)&dp[w * 32 + 16 + lr][ks + 8 * lg];
#pragma unroll
      for (int nt = 0; nt < 8; ++nt) {
        bf16x8 bb = *(const bf16x8*)(qpp + (long)nt * 16 * NH + ks);
        s[0][nt] = MFMA16(a0, bb, s[0][nt]);
        s[1][nt] = MFMA16(a1, bb, s[1][nt]);
      }
    }
  }
  __syncthreads();  // all dp reads complete before p_lds overlay is written

  // stage 3: softmax over q, write P bf16 to p_lds (own rows only)
#pragma unroll
  for (int mt = 0; mt < 2; ++mt) {
    f32x4 mx;
#pragma unroll
    for (int r = 0; r < 4; ++r) {
      float m = s[mt][0][r];
#pragma unroll
      for (int nt = 1; nt < 8; ++nt) m = fmaxf(m, s[mt][nt][r]);
      mx[r] = m;
    }
#pragma unroll
    for (int d = 1; d < 16; d <<= 1)
#pragma unroll
      for (int r = 0; r < 4; ++r) mx[r] = fmaxf(mx[r], __shfl_xor(mx[r], d));
    f32x4 sum = {};
#pragma unroll
    for (int nt = 0; nt < 8; ++nt)
#pragma unroll
      for (int r = 0; r < 4; ++r) {
        float p = __expf(s[mt][nt][r] - mx[r]);
        s[mt][nt][r] = p;
        sum[r] += p;
      }
#pragma unroll
    for (int d = 1; d < 16; d <<= 1)
#pragma unroll
      for (int r = 0; r < 4; ++r) sum[r] += __shfl_xor(sum[r], d);
    f32x4 inv;
#pragma unroll
    for (int r = 0; r < 4; ++r) inv[r] = 1.0f / sum[r];
#pragma unroll
    for (int nt = 0; nt < 8; ++nt)
#pragma unroll
      for (int r = 0; r < 4; ++r)
        p_lds[w * 32 + mt * 16 + 4 * lg + r][nt * 16 + lr] = f2bf(s[mt][nt][r] * inv[r]);
  }
  // own-row reads in stage 4 -> no barrier

  // stage 4: prealign = P @ query_e[b] (K = 128) -> doc_out cols 300:600 f32
  const u16* qtp = qeT + (long)b * QETN * NQ;
  bf16x8 pa[2][4];  // invariant A-fragments hoisted out of the nt loop
#pragma unroll
  for (int mt = 0; mt < 2; ++mt)
#pragma unroll
    for (int ksi = 0; ksi < 4; ++ksi)
      pa[mt][ksi] = *(const bf16x8*)&p_lds[w * 32 + mt * 16 + lr][ksi * 32 + 8 * lg];
#pragma unroll 2
  for (int nt = 0; nt < 19; ++nt) {
    f32x4 acc0 = {}, acc1 = {};
#pragma unroll
    for (int ksi = 0; ksi < 4; ++ksi) {
      bf16x8 bb = *(const bf16x8*)(qtp + (long)(nt * 16 + lr) * NQ + ksi * 32 + 8 * lg);
      acc0 = MFMA16(pa[0][ksi], bb, acc0);
      acc1 = MFMA16(pa[1][ksi], bb, acc1);
    }
    int col = nt * 16 + lr;
    if (col < NE) {
#pragma unroll
      for (int r = 0; r < 4; ++r) {
        long rl0 = blkrow + w * 32 + 4 * lg + r;
        doc_out[rl0 * DOC_W + 300 + col] = acc0[r];
        doc_out[(rl0 + 16) * DOC_W + 300 + col] = acc1[r];
      }
    }
  }
}

extern "C" void kernel_launch(void* const* d_in, const int* in_sizes, int n_in,
                              void* d_out, int out_size, void* d_ws, size_t ws_size,
                              hipStream_t stream) {
  // Size-based dispatch (R3/R4: identical to dict order; kept for robustness).
  const int *query_tok = nullptr, *doc_tok = nullptr, *doc_pos = nullptr, *doc_ner = nullptr;
  const float *doc_fea = nullptr, *word_emb = nullptr, *proj_w = nullptr,
              *proj_b = nullptr, *pos_emb = nullptr, *ner_emb = nullptr;
  int n65536 = 0;
  for (int i = 0; i < n_in; ++i) {
    switch (in_sizes[i]) {
      case 15000000: word_emb  = (const float*)d_in[i]; break;  // 50000*300
      case 262144:   doc_fea   = (const float*)d_in[i]; break;  // 64*1024*4
      case 76800:    proj_w    = (const float*)d_in[i]; break;  // 300*256
      case 8192:     query_tok = (const int*)d_in[i];   break;  // 64*128
      case 256:      proj_b    = (const float*)d_in[i]; break;
      case 672:      pos_emb   = (const float*)d_in[i]; break;  // 56*12
      case 152:      ner_emb   = (const float*)d_in[i]; break;  // 19*8
      case 65536:                                               // 64*1024 ints
        if (n65536 == 0)      doc_tok = (const int*)d_in[i];
        else if (n65536 == 1) doc_pos = (const int*)d_in[i];
        else                  doc_ner = (const int*)d_in[i];
        ++n65536; break;
      default: break;
    }
  }

  float* out = (float*)d_out;
  float* q_out   = out;                         // [B*Q][300] f32
  float* doc_out = out + (size_t)NB * NQ * NE;  // [B*D][624] f32

  char* ws = (char*)d_ws;
  u16* Wt  = (u16*)ws; ws += (size_t)NH * KP * 2;        // 160 KB
  u16* qP  = (u16*)ws; ws += (size_t)NB * NQ * NH * 2;   // 4 MB
  u16* qeT = (u16*)ws; ws += (size_t)NB * QETN * NQ * 2; // 4.75 MB

  k_pre<<<dim3(1320), dim3(1024), 0, stream>>>(
      proj_w, Wt, query_tok, word_emb, q_out, qeT,
      doc_ner, doc_pos, doc_fea, ner_emb, pos_emb, doc_out, proj_b, qP);
  k_fused<<<dim3(512), dim3(256), 0, stream>>>(
      doc_tok, word_emb, doc_out, Wt, proj_b, qP, qeT);
}

// Round 18
// 120.615 us; speedup vs baseline: 1.6456x; 1.0002x over previous
//
#include <hip/hip_runtime.h>
#include <hip/hip_bf16.h>

typedef unsigned short u16;
typedef __attribute__((ext_vector_type(8))) short bf16x8;
typedef __attribute__((ext_vector_type(4))) float f32x4;

#define MFMA16(a, b, c) __builtin_amdgcn_mfma_f32_16x16x32_bf16((a), (b), (c), 0, 0, 0)

#define NB 64
#define ND 1024
#define NQ 128
#define NE 300
#define NH 256
#define KP 320
#define QETN 304
#define DOC_W 624

static __device__ __forceinline__ u16 f2bf(float f) {
  union { __bf16 h; u16 u; } c; c.h = (__bf16)f; return c.u;
}

static __device__ __forceinline__ bf16x8 pack8(float4 f0, float4 f1) {
  union { bf16x8 v; u16 u[8]; } r;
  r.u[0] = f2bf(f0.x); r.u[1] = f2bf(f0.y); r.u[2] = f2bf(f0.z); r.u[3] = f2bf(f0.w);
  r.u[4] = f2bf(f1.x); r.u[5] = f2bf(f1.y); r.u[6] = f2bf(f1.z); r.u[7] = f2bf(f1.w);
  return r.v;
}

// ---- k_pre (1024-thread blocks; R17-verified):
// [0,80) Wt | [80,680) query embed | [680,1064) extras | [1064,1192) qeT | [1192,1320) qP
__global__ void k_pre(const float* __restrict__ w, u16* __restrict__ wt,
                      const int* __restrict__ qtok, const float* __restrict__ emb,
                      float* __restrict__ q_out, u16* __restrict__ qet,
                      const int* __restrict__ ner, const int* __restrict__ pos,
                      const float* __restrict__ fea,
                      const float* __restrict__ ner_emb, const float* __restrict__ pos_emb,
                      float* __restrict__ doc_out,
                      const float* __restrict__ bias, u16* __restrict__ qP) {
  __shared__ u16 T[64][322];  // stride 322: bank-stride 161%32==1 -> conflict-free
  int bx = blockIdx.x, tid = threadIdx.x;
  if (bx < 80) {
    int idx = bx * 1024 + tid;  // exactly NH*KP = 81920
    int n = idx / KP, k = idx % KP;
    wt[idx] = (k < NE) ? f2bf(w[k * NH + n]) : (u16)0;
  } else if (bx < 680) {
    int idx = (bx - 80) * 1024 + tid;  // exactly 8192*75
    int row = idx / 75, j = (idx % 75) * 4;
    float4 v = {0.f, 0.f, 0.f, 0.f};
    int t = qtok[row];
    if (t != 0) v = *(const float4*)(emb + (long)t * NE + j);
    *(float4*)(q_out + (long)row * NE + j) = v;
  } else if (bx < 1064) {
    int idx = (bx - 680) * 1024 + tid;  // exactly 65536*6
    int row = idx / 6, c0 = (idx % 6) * 4;
    float4 v;
    float* vp = (float*)&v;
#pragma unroll
    for (int u = 0; u < 4; ++u) {
      int c = c0 + u;
      float x;
      if (c < 8)       { int t = ner[row]; x = t ? ner_emb[t * 8 + c] : 0.f; }
      else if (c < 20) { int t = pos[row]; x = t ? pos_emb[t * 12 + (c - 8)] : 0.f; }
      else             { x = fea[(long)row * 4 + (c - 20)]; }
      vp[u] = x;
    }
    *(float4*)(doc_out + (long)row * DOC_W + 600 + c0) = v;
  } else if (bx < 1192) {
    // qeT[b][n][k] = bf16(query_e[b*128+k0+..][n]); n in [300,304) -> 0
    int bxx = bx - 1064;
    int b = bxx >> 1, k0 = (bxx & 1) * 64;
    for (int i = tid; i < 64 * 75; i += 1024) {
      int row = i / 75, j = (i % 75) * 4;
      int t = qtok[b * NQ + k0 + row];
      float4 f = {0.f, 0.f, 0.f, 0.f};
      if (t != 0) f = *(const float4*)(emb + (long)t * NE + j);
      T[row][j]     = f2bf(f.x); T[row][j + 1] = f2bf(f.y);
      T[row][j + 2] = f2bf(f.z); T[row][j + 3] = f2bf(f.w);
    }
    __syncthreads();
    u16* dst = qet + (long)b * QETN * NQ + k0;
    for (int i = tid; i < QETN * 16; i += 1024) {
      int n = i / 16, kq = (i % 16) * 4;
      u16 v[4] = {0, 0, 0, 0};
      if (n < NE) {
        v[0] = T[kq][n]; v[1] = T[kq + 1][n]; v[2] = T[kq + 2][n]; v[3] = T[kq + 3][n];
      }
      *(uint2*)(dst + (long)n * NQ + kq) = *(const uint2*)v;
    }
  } else {
    // qP: block = 256 q-rows x 64 cols; 16 waves, wave wv = rows [bm0,bm0+16).
    int bx2 = bx - 1192;              // [0,128)
    int rowg = bx2 >> 2, colg = bx2 & 3;
    int ncol0 = colg * 64;
    // stage Wt slice: T[n][k] = bf16(proj_w[k][ncol0+n]) for ALL k in [0,300)
    for (int i = tid; i < 300 * 64; i += 1024) {
      int n = i & 63, k = i >> 6;
      T[n][k] = f2bf(w[k * NH + ncol0 + n]);
    }
    for (int i = tid; i < 64 * 22; i += 1024)
      T[i / 22][300 + (i % 22)] = 0;
    __syncthreads();
    int l = tid & 63, wv = tid >> 6;
    int lr = l & 15, lg = l >> 4, c0 = 8 * lg;
    int bm0 = rowg * 256 + wv * 16;
    const float* ar = emb + (long)qtok[bm0 + lr] * NE;  // tok 0 -> zero row of emb
    f32x4 acc[4] = {};
#pragma unroll 3
    for (int ks = 0; ks < 288; ks += 32) {  // cols <= 288 < 300: unmasked
      bf16x8 a0 = pack8(*(const float4*)(ar + ks + c0), *(const float4*)(ar + ks + c0 + 4));
#pragma unroll
      for (int nt = 0; nt < 4; ++nt) {
        bf16x8 bb = *(const bf16x8*)&T[nt * 16 + lr][ks + c0];
        acc[nt] = MFMA16(a0, bb, acc[nt]);
      }
    }
    {  // tail ks=288: mask loads past col 300; T zero there
      const int ks = 288;
      int col = ks + c0;
      float4 z = {0.f, 0.f, 0.f, 0.f};
      float4 f0 = (col + 4 <= NE) ? *(const float4*)(ar + col) : z;
      float4 f1 = (col + 8 <= NE) ? *(const float4*)(ar + col + 4) : z;
      bf16x8 a0 = pack8(f0, f1);
#pragma unroll
      for (int nt = 0; nt < 4; ++nt) {
        bf16x8 bb = *(const bf16x8*)&T[nt * 16 + lr][ks + c0];
        acc[nt] = MFMA16(a0, bb, acc[nt]);
      }
    }
#pragma unroll
    for (int nt = 0; nt < 4; ++nt) {
      int col = ncol0 + nt * 16 + lr;
      float bv = bias[col];
#pragma unroll
      for (int r = 0; r < 4; ++r) {
        int row = bm0 + 4 * lg + r;
        float v = acc[nt][r] + bv;
        v = v > 0.f ? v : 0.f;
        qP[(long)row * NH + col] = f2bf(v);
      }
    }
  }
}

// ---- fused: doc embed gather + d_proj (LDS) -> scores -> softmax -> prealign ----
// R17 structure; stage-1 K-loop FULLY unrolled: occupancy is LDS-capped at
// 2 blocks/CU (8 waves) regardless of VGPR, so the ~130 free registers
// (VGPR_Count was 116/256) become compiler-managed load-pipeline depth.
__launch_bounds__(256, 2)
__global__ void k_fused(const int* __restrict__ dtok, const float* __restrict__ emb,
                        float* doc_out, const u16* __restrict__ Wt,
                        const float* __restrict__ bias,
                        const u16* __restrict__ qP, const u16* __restrict__ qeT) {
  __shared__ __align__(16) u16 dp[128][264];
  u16 (*p_lds)[136] = (u16 (*)[136]) & dp[0][0];
  int bid = blockIdx.x;
  int xcd = bid & 7, j = bid >> 3;
  int b = xcd * 8 + (j >> 3);
  int chunk = j & 7;
  int l = threadIdx.x & 63, w = threadIdx.x >> 6;
  int lr = l & 15, lg = l >> 4;
  long blkrow = (long)b * ND + chunk * 128;

  // stage 1: gather + d_proj tile -> dp. Wave w: rows (w&1)*64+[0,64), cols (w>>1)*128+[0,128)
  {
    int mrow0 = (w & 1) * 64;
    int ncol0 = (w >> 1) * 128;
    bool wr = (w >> 1) == 0;  // only col-wave 0 writes doc_out
    const float* arow[4];
    float* drow[4];
#pragma unroll
    for (int mt = 0; mt < 4; ++mt) {
      long r = blkrow + mrow0 + mt * 16 + lr;
      arow[mt] = emb + (long)dtok[r] * NE;
      drow[mt] = doc_out + r * DOC_W;
    }
    const u16* wp = Wt + (long)(ncol0 + lr) * KP + 8 * lg;
    f32x4 acc[4][8] = {};
    int c0 = 8 * lg;
#pragma unroll
    for (int ks = 0; ks < 288; ks += 32) {  // FULL unroll (9 steps): deep load pipeline
      bf16x8 a[4];
#pragma unroll
      for (int mt = 0; mt < 4; ++mt) {
        int col = ks + c0;
        float4 f0 = *(const float4*)(arow[mt] + col);
        float4 f1 = *(const float4*)(arow[mt] + col + 4);
        if (wr) {
          *(float4*)(drow[mt] + col) = f0;
          *(float4*)(drow[mt] + col + 4) = f1;
        }
        a[mt] = pack8(f0, f1);
      }
#pragma unroll
      for (int nt = 0; nt < 8; ++nt) {
        bf16x8 bb = *(const bf16x8*)(wp + nt * 16 * KP + ks);
#pragma unroll
        for (int mt = 0; mt < 4; ++mt) acc[mt][nt] = MFMA16(a[mt], bb, acc[mt][nt]);
      }
    }
    {  // K-tail ks=288: cols 288..319; mask loads past col 300 (table-end OOB)
      const int ks = 288;
      int col = ks + c0;
      float4 z = {0.f, 0.f, 0.f, 0.f};
      bf16x8 a[4];
#pragma unroll
      for (int mt = 0; mt < 4; ++mt) {
        float4 f0 = (col + 4 <= NE) ? *(const float4*)(arow[mt] + col) : z;
        float4 f1 = (col + 8 <= NE) ? *(const float4*)(arow[mt] + col + 4) : z;
        if (wr) {
          if (col + 4 <= NE) *(float4*)(drow[mt] + col) = f0;
          if (col + 8 <= NE) *(float4*)(drow[mt] + col + 4) = f1;
        }
        a[mt] = pack8(f0, f1);
      }
#pragma unroll
      for (int nt = 0; nt < 8; ++nt) {
        bf16x8 bb = *(const bf16x8*)(wp + nt * 16 * KP + ks);
#pragma unroll
        for (int mt = 0; mt < 4; ++mt) acc[mt][nt] = MFMA16(a[mt], bb, acc[mt][nt]);
      }
    }
#pragma unroll
    for (int nt = 0; nt < 8; ++nt) {
      int col = ncol0 + nt * 16 + lr;
      float bv = bias[col];
#pragma unroll
      for (int mt = 0; mt < 4; ++mt)
#pragma unroll
        for (int r = 0; r < 4; ++r) {
          float v = acc[mt][nt][r] + bv;
          dp[mrow0 + mt * 16 + 4 * lg + r][col] = f2bf(v > 0.f ? v : 0.f);
        }
    }
  }
  __syncthreads();  // dp rows are cross-wave from here on

  // stage 2: scores S[32][128] per wave (rows w*32..), K = 256
  f32x4 s[2][8] = {};
  {
    const u16* qpp = qP + ((long)b * NQ + lr) * NH + 8 * lg;
#pragma unroll
    for (int ks = 0; ks < NH; ks += 32) {
      bf16x8 a0 = *(const bf16x8*)&dp[w * 32 + lr][ks + 8 * lg];
      bf16x8 a1 = *(const bf16x8*)&dp[w * 32 + 16 + lr][ks + 8 * lg];
#pragma unroll
      for (int nt = 0; nt < 8; ++nt) {
        bf16x8 bb = *(const bf16x8*)(qpp + (long)nt * 16 * NH + ks);
        s[0][nt] = MFMA16(a0, bb, s[0][nt]);
        s[1][nt] = MFMA16(a1, bb, s[1][nt]);
      }
    }
  }
  __syncthreads();  // all dp reads complete before p_lds overlay is written

  // stage 3: softmax over q, write P bf16 to p_lds (own rows only)
#pragma unroll
  for (int mt = 0; mt < 2; ++mt) {
    f32x4 mx;
#pragma unroll
    for (int r = 0; r < 4; ++r) {
      float m = s[mt][0][r];
#pragma unroll
      for (int nt = 1; nt < 8; ++nt) m = fmaxf(m, s[mt][nt][r]);
      mx[r] = m;
    }
#pragma unroll
    for (int d = 1; d < 16; d <<= 1)
#pragma unroll
      for (int r = 0; r < 4; ++r) mx[r] = fmaxf(mx[r], __shfl_xor(mx[r], d));
    f32x4 sum = {};
#pragma unroll
    for (int nt = 0; nt < 8; ++nt)
#pragma unroll
      for (int r = 0; r < 4; ++r) {
        float p = __expf(s[mt][nt][r] - mx[r]);
        s[mt][nt][r] = p;
        sum[r] += p;
      }
#pragma unroll
    for (int d = 1; d < 16; d <<= 1)
#pragma unroll
      for (int r = 0; r < 4; ++r) sum[r] += __shfl_xor(sum[r], d);
    f32x4 inv;
#pragma unroll
    for (int r = 0; r < 4; ++r) inv[r] = 1.0f / sum[r];
#pragma unroll
    for (int nt = 0; nt < 8; ++nt)
#pragma unroll
      for (int r = 0; r < 4; ++r)
        p_lds[w * 32 + mt * 16 + 4 * lg + r][nt * 16 + lr] = f2bf(s[mt][nt][r] * inv[r]);
  }
  // own-row reads in stage 4 -> no barrier

  // stage 4: prealign = P @ query_e[b] (K = 128) -> doc_out cols 300:600 f32
  const u16* qtp = qeT + (long)b * QETN * NQ;
  bf16x8 pa[2][4];  // invariant A-fragments hoisted out of the nt loop
#pragma unroll
  for (int mt = 0; mt < 2; ++mt)
#pragma unroll
    for (int ksi = 0; ksi < 4; ++ksi)
      pa[mt][ksi] = *(const bf16x8*)&p_lds[w * 32 + mt * 16 + lr][ksi * 32 + 8 * lg];
#pragma unroll 2
  for (int nt = 0; nt < 19; ++nt) {
    f32x4 acc0 = {}, acc1 = {};
#pragma unroll
    for (int ksi = 0; ksi < 4; ++ksi) {
      bf16x8 bb = *(const bf16x8*)(qtp + (long)(nt * 16 + lr) * NQ + ksi * 32 + 8 * lg);
      acc0 = MFMA16(pa[0][ksi], bb, acc0);
      acc1 = MFMA16(pa[1][ksi], bb, acc1);
    }
    int col = nt * 16 + lr;
    if (col < NE) {
#pragma unroll
      for (int r = 0; r < 4; ++r) {
        long rl0 = blkrow + w * 32 + 4 * lg + r;
        doc_out[rl0 * DOC_W + 300 + col] = acc0[r];
        doc_out[(rl0 + 16) * DOC_W + 300 + col] = acc1[r];
      }
    }
  }
}

extern "C" void kernel_launch(void* const* d_in, const int* in_sizes, int n_in,
                              void* d_out, int out_size, void* d_ws, size_t ws_size,
                              hipStream_t stream) {
  // Size-based dispatch (R3/R4: identical to dict order; kept for robustness).
  const int *query_tok = nullptr, *doc_tok = nullptr, *doc_pos = nullptr, *doc_ner = nullptr;
  const float *doc_fea = nullptr, *word_emb = nullptr, *proj_w = nullptr,
              *proj_b = nullptr, *pos_emb = nullptr, *ner_emb = nullptr;
  int n65536 = 0;
  for (int i = 0; i < n_in; ++i) {
    switch (in_sizes[i]) {
      case 15000000: word_emb  = (const float*)d_in[i]; break;  // 50000*300
      case 262144:   doc_fea   = (const float*)d_in[i]; break;  // 64*1024*4
      case 76800:    proj_w    = (const float*)d_in[i]; break;  // 300*256
      case 8192:     query_tok = (const int*)d_in[i];   break;  // 64*128
      case 256:      proj_b    = (const float*)d_in[i]; break;
      case 672:      pos_emb   = (const float*)d_in[i]; break;  // 56*12
      case 152:      ner_emb   = (const float*)d_in[i]; break;  // 19*8
      case 65536:                                               // 64*1024 ints
        if (n65536 == 0)      doc_tok = (const int*)d_in[i];
        else if (n65536 == 1) doc_pos = (const int*)d_in[i];
        else                  doc_ner = (const int*)d_in[i];
        ++n65536; break;
      default: break;
    }
  }

  float* out = (float*)d_out;
  float* q_out   = out;                         // [B*Q][300] f32
  float* doc_out = out + (size_t)NB * NQ * NE;  // [B*D][624] f32

  char* ws = (char*)d_ws;
  u16* Wt  = (u16*)ws; ws += (size_t)NH * KP * 2;        // 160 KB
  u16* qP  = (u16*)ws; ws += (size_t)NB * NQ * NH * 2;   // 4 MB
  u16* qeT = (u16*)ws; ws += (size_t)NB * QETN * NQ * 2; // 4.75 MB

  k_pre<<<dim3(1320), dim3(1024), 0, stream>>>(
      proj_w, Wt, query_tok, word_emb, q_out, qeT,
      doc_ner, doc_pos, doc_fea, ner_emb, pos_emb, doc_out, proj_b, qP);
  k_fused<<<dim3(512), dim3(256), 0, stream>>>(
      doc_tok, word_emb, doc_out, Wt, proj_b, qP, qeT);
}

// Round 19
// 111.902 us; speedup vs baseline: 1.7737x; 1.0779x over previous
//
#include <hip/hip_runtime.h>
#include <hip/hip_bf16.h>

typedef unsigned short u16;
typedef __attribute__((ext_vector_type(8))) short bf16x8;
typedef __attribute__((ext_vector_type(4))) float f32x4;

#define MFMA16(a, b, c) __builtin_amdgcn_mfma_f32_16x16x32_bf16((a), (b), (c), 0, 0, 0)

#define NB 64
#define ND 1024
#define NQ 128
#define NE 300
#define NH 256
#define KP 320
#define QETN 304
#define EBW 304   // embB row stride (u16), 16B-aligned rows
#define DOC_W 624

static __device__ __forceinline__ u16 f2bf(float f) {
  union { __bf16 h; u16 u; } c; c.h = (__bf16)f; return c.u;
}

static __device__ __forceinline__ bf16x8 pack8(float4 f0, float4 f1) {
  union { bf16x8 v; u16 u[8]; } r;
  r.u[0] = f2bf(f0.x); r.u[1] = f2bf(f0.y); r.u[2] = f2bf(f0.z); r.u[3] = f2bf(f0.w);
  r.u[4] = f2bf(f1.x); r.u[5] = f2bf(f1.y); r.u[6] = f2bf(f1.z); r.u[7] = f2bf(f1.w);
  return r.v;
}

static __device__ __forceinline__ float bf2f(u16 u) {
  union { float f; unsigned i; } x; x.i = ((unsigned)u) << 16; return x.f;
}

static __device__ __forceinline__ void bf8_to_f32(bf16x8 v, float4& f0, float4& f1) {
  union { bf16x8 b; u16 u[8]; } x; x.b = v;
  f0.x = bf2f(x.u[0]); f0.y = bf2f(x.u[1]); f0.z = bf2f(x.u[2]); f0.w = bf2f(x.u[3]);
  f1.x = bf2f(x.u[4]); f1.y = bf2f(x.u[5]); f1.z = bf2f(x.u[6]); f1.w = bf2f(x.u[7]);
}

// ---- k_pre (1024-thread blocks):
// [0,80) Wt | [80,680) query embed | [680,1064) extras | [1064,1192) qeT |
// [1192,1320) qP | [1320,5031) embB: bf16 vocab table [50000][304]
__global__ void k_pre(const float* __restrict__ w, u16* __restrict__ wt,
                      const int* __restrict__ qtok, const float* __restrict__ emb,
                      float* __restrict__ q_out, u16* __restrict__ qet,
                      const int* __restrict__ ner, const int* __restrict__ pos,
                      const float* __restrict__ fea,
                      const float* __restrict__ ner_emb, const float* __restrict__ pos_emb,
                      float* __restrict__ doc_out,
                      const float* __restrict__ bias, u16* __restrict__ qP,
                      u16* __restrict__ embB) {
  __shared__ u16 T[64][322];  // stride 322: bank-stride 161%32==1 -> conflict-free
  int bx = blockIdx.x, tid = threadIdx.x;
  if (bx < 80) {
    int idx = bx * 1024 + tid;  // exactly NH*KP = 81920
    int n = idx / KP, k = idx % KP;
    wt[idx] = (k < NE) ? f2bf(w[k * NH + n]) : (u16)0;
  } else if (bx < 680) {
    int idx = (bx - 80) * 1024 + tid;  // exactly 8192*75
    int row = idx / 75, j = (idx % 75) * 4;
    float4 v = {0.f, 0.f, 0.f, 0.f};
    int t = qtok[row];
    if (t != 0) v = *(const float4*)(emb + (long)t * NE + j);
    *(float4*)(q_out + (long)row * NE + j) = v;
  } else if (bx < 1064) {
    int idx = (bx - 680) * 1024 + tid;  // exactly 65536*6
    int row = idx / 6, c0 = (idx % 6) * 4;
    float4 v;
    float* vp = (float*)&v;
#pragma unroll
    for (int u = 0; u < 4; ++u) {
      int c = c0 + u;
      float x;
      if (c < 8)       { int t = ner[row]; x = t ? ner_emb[t * 8 + c] : 0.f; }
      else if (c < 20) { int t = pos[row]; x = t ? pos_emb[t * 12 + (c - 8)] : 0.f; }
      else             { x = fea[(long)row * 4 + (c - 20)]; }
      vp[u] = x;
    }
    *(float4*)(doc_out + (long)row * DOC_W + 600 + c0) = v;
  } else if (bx < 1192) {
    // qeT[b][n][k] = bf16(query_e[b*128+k0+..][n]); n in [300,304) -> 0
    int bxx = bx - 1064;
    int b = bxx >> 1, k0 = (bxx & 1) * 64;
    for (int i = tid; i < 64 * 75; i += 1024) {
      int row = i / 75, j = (i % 75) * 4;
      int t = qtok[b * NQ + k0 + row];
      float4 f = {0.f, 0.f, 0.f, 0.f};
      if (t != 0) f = *(const float4*)(emb + (long)t * NE + j);
      T[row][j]     = f2bf(f.x); T[row][j + 1] = f2bf(f.y);
      T[row][j + 2] = f2bf(f.z); T[row][j + 3] = f2bf(f.w);
    }
    __syncthreads();
    u16* dst = qet + (long)b * QETN * NQ + k0;
    for (int i = tid; i < QETN * 16; i += 1024) {
      int n = i / 16, kq = (i % 16) * 4;
      u16 v[4] = {0, 0, 0, 0};
      if (n < NE) {
        v[0] = T[kq][n]; v[1] = T[kq + 1][n]; v[2] = T[kq + 2][n]; v[3] = T[kq + 3][n];
      }
      *(uint2*)(dst + (long)n * NQ + kq) = *(const uint2*)v;
    }
  } else if (bx < 1320) {
    // qP: block = 256 q-rows x 64 cols; 16 waves, wave wv = rows [bm0,bm0+16).
    int bx2 = bx - 1192;              // [0,128)
    int rowg = bx2 >> 2, colg = bx2 & 3;
    int ncol0 = colg * 64;
    for (int i = tid; i < 300 * 64; i += 1024) {
      int n = i & 63, k = i >> 6;
      T[n][k] = f2bf(w[k * NH + ncol0 + n]);
    }
    for (int i = tid; i < 64 * 22; i += 1024)
      T[i / 22][300 + (i % 22)] = 0;
    __syncthreads();
    int l = tid & 63, wv = tid >> 6;
    int lr = l & 15, lg = l >> 4, c0 = 8 * lg;
    int bm0 = rowg * 256 + wv * 16;
    const float* ar = emb + (long)qtok[bm0 + lr] * NE;  // tok 0 -> zero row of emb
    f32x4 acc[4] = {};
#pragma unroll 3
    for (int ks = 0; ks < 288; ks += 32) {
      bf16x8 a0 = pack8(*(const float4*)(ar + ks + c0), *(const float4*)(ar + ks + c0 + 4));
#pragma unroll
      for (int nt = 0; nt < 4; ++nt) {
        bf16x8 bb = *(const bf16x8*)&T[nt * 16 + lr][ks + c0];
        acc[nt] = MFMA16(a0, bb, acc[nt]);
      }
    }
    {
      const int ks = 288;
      int col = ks + c0;
      float4 z = {0.f, 0.f, 0.f, 0.f};
      float4 f0 = (col + 4 <= NE) ? *(const float4*)(ar + col) : z;
      float4 f1 = (col + 8 <= NE) ? *(const float4*)(ar + col + 4) : z;
      bf16x8 a0 = pack8(f0, f1);
#pragma unroll
      for (int nt = 0; nt < 4; ++nt) {
        bf16x8 bb = *(const bf16x8*)&T[nt * 16 + lr][ks + c0];
        acc[nt] = MFMA16(a0, bb, acc[nt]);
      }
    }
#pragma unroll
    for (int nt = 0; nt < 4; ++nt) {
      int col = ncol0 + nt * 16 + lr;
      float bv = bias[col];
#pragma unroll
      for (int r = 0; r < 4; ++r) {
        int row = bm0 + 4 * lg + r;
        float v = acc[nt][r] + bv;
        v = v > 0.f ? v : 0.f;
        qP[(long)row * NH + col] = f2bf(v);
      }
    }
  } else {
    // embB[v][j] = bf16(word_emb[v][j]) for j<300, 0 for j in [300,304).
    int idx = (bx - 1320) * 1024 + tid;  // 50000*76 = 3.8M groups of 4 cols
    if (idx < 50000 * 76) {
      int v = idx / 76, j = (idx % 76) * 4;
      u16 o[4] = {0, 0, 0, 0};
      if (j < NE) {
        float4 f = *(const float4*)(emb + (long)v * NE + j);
        o[0] = f2bf(f.x); o[1] = f2bf(f.y); o[2] = f2bf(f.z); o[3] = f2bf(f.w);
      }
      *(uint2*)(embB + (long)v * EBW + j) = *(const uint2*)o;
    }
  }
}

// ---- fused: bf16 gather + d_proj (LDS) -> scores -> softmax -> prealign ----
// Stage 1 gathers 600B bf16 rows from embB (half R17's bytes); each 16B load IS
// an MFMA fragment (no pack). 2 K-steps/iter keeps 8 gather loads in flight
// (R9/R11 lesson: in-flight count is the binding resource). doc_e f32 written
// from the bf16 registers (rounding ~2e-3, threshold 9.25e-2).
__launch_bounds__(256, 2)
__global__ void k_fused(const int* __restrict__ dtok, const u16* __restrict__ embB,
                        float* doc_out, const u16* __restrict__ Wt,
                        const float* __restrict__ bias,
                        const u16* __restrict__ qP, const u16* __restrict__ qeT) {
  __shared__ __align__(16) u16 dp[128][264];
  u16 (*p_lds)[136] = (u16 (*)[136]) & dp[0][0];
  int bid = blockIdx.x;
  int xcd = bid & 7, j = bid >> 3;
  int b = xcd * 8 + (j >> 3);
  int chunk = j & 7;
  int l = threadIdx.x & 63, w = threadIdx.x >> 6;
  int lr = l & 15, lg = l >> 4;
  long blkrow = (long)b * ND + chunk * 128;
  int c0 = 8 * lg;

  // stage 1: bf16 gather + d_proj tile -> dp. Wave w: rows (w&1)*64+[0,64), cols (w>>1)*128
  {
    int mrow0 = (w & 1) * 64;
    int ncol0 = (w >> 1) * 128;
    bool wr = (w >> 1) == 0;  // only col-wave 0 writes doc_out cols 0:300
    const u16* arow[4];
    float* drow[4];
#pragma unroll
    for (int mt = 0; mt < 4; ++mt) {
      long r = blkrow + mrow0 + mt * 16 + lr;
      arow[mt] = embB + (long)dtok[r] * EBW;
      drow[mt] = doc_out + r * DOC_W;
    }
    const u16* wp = Wt + (long)(ncol0 + lr) * KP + c0;
    f32x4 acc[4][8] = {};
#pragma unroll
    for (int it = 0; it < 5; ++it) {  // 2 K-steps per iter: 8 gather loads in flight
      int ks0 = it * 64, ks1 = ks0 + 32;
      bf16x8 A0[4], A1[4];
#pragma unroll
      for (int mt = 0; mt < 4; ++mt) {
        A0[mt] = *(const bf16x8*)(arow[mt] + ks0 + c0);
        // ks1=288 rows: cols past 300 read embB zero-pad / next-row junk,
        // multiplied by zero Wt rows [300,320) -> exact 0. In-bounds via +64 pad.
        A1[mt] = *(const bf16x8*)(arow[mt] + ks1 + c0);
      }
      if (wr) {
#pragma unroll
        for (int mt = 0; mt < 4; ++mt) {
          float4 f0, f1;
          bf8_to_f32(A0[mt], f0, f1);  // ks0 cols <= 256+24+8 = 288 < 300: unmasked
          *(float4*)(drow[mt] + ks0 + c0) = f0;
          *(float4*)(drow[mt] + ks0 + c0 + 4) = f1;
          float4 g0, g1;
          bf8_to_f32(A1[mt], g0, g1);
          int col1 = ks1 + c0;
          if (col1 + 4 <= NE) *(float4*)(drow[mt] + col1) = g0;
          if (col1 + 8 <= NE) *(float4*)(drow[mt] + col1 + 4) = g1;
        }
      }
#pragma unroll
      for (int nt = 0; nt < 8; ++nt) {
        bf16x8 b0 = *(const bf16x8*)(wp + nt * 16 * KP + ks0);
        bf16x8 b1 = *(const bf16x8*)(wp + nt * 16 * KP + ks1);
#pragma unroll
        for (int mt = 0; mt < 4; ++mt) {
          acc[mt][nt] = MFMA16(A0[mt], b0, acc[mt][nt]);
          acc[mt][nt] = MFMA16(A1[mt], b1, acc[mt][nt]);
        }
      }
    }
#pragma unroll
    for (int nt = 0; nt < 8; ++nt) {
      int col = ncol0 + nt * 16 + lr;
      float bv = bias[col];
#pragma unroll
      for (int mt = 0; mt < 4; ++mt)
#pragma unroll
        for (int r = 0; r < 4; ++r) {
          float v = acc[mt][nt][r] + bv;
          dp[mrow0 + mt * 16 + 4 * lg + r][col] = f2bf(v > 0.f ? v : 0.f);
        }
    }
  }
  __syncthreads();  // dp rows are cross-wave from here on

  // stage 2: scores S[32][128] per wave (rows w*32..), K = 256
  f32x4 s[2][8] = {};
  {
    const u16* qpp = qP + ((long)b * NQ + lr) * NH + 8 * lg;
#pragma unroll
    for (int ks = 0; ks < NH; ks += 32) {
      bf16x8 a0 = *(const bf16x8*)&dp[w * 32 + lr][ks + 8 * lg];
      bf16x8 a1 = *(const bf16x8*)&dp[w * 32 + 16 + lr][ks + 8 * lg];
#pragma unroll
      for (int nt = 0; nt < 8; ++nt) {
        bf16x8 bb = *(const bf16x8*)(qpp + (long)nt * 16 * NH + ks);
        s[0][nt] = MFMA16(a0, bb, s[0][nt]);
        s[1][nt] = MFMA16(a1, bb, s[1][nt]);
      }
    }
  }
  __syncthreads();  // all dp reads complete before p_lds overlay is written

  // stage 3: softmax over q, write P bf16 to p_lds (own rows only)
#pragma unroll
  for (int mt = 0; mt < 2; ++mt) {
    f32x4 mx;
#pragma unroll
    for (int r = 0; r < 4; ++r) {
      float m = s[mt][0][r];
#pragma unroll
      for (int nt = 1; nt < 8; ++nt) m = fmaxf(m, s[mt][nt][r]);
      mx[r] = m;
    }
#pragma unroll
    for (int d = 1; d < 16; d <<= 1)
#pragma unroll
      for (int r = 0; r < 4; ++r) mx[r] = fmaxf(mx[r], __shfl_xor(mx[r], d));
    f32x4 sum = {};
#pragma unroll
    for (int nt = 0; nt < 8; ++nt)
#pragma unroll
      for (int r = 0; r < 4; ++r) {
        float p = __expf(s[mt][nt][r] - mx[r]);
        s[mt][nt][r] = p;
        sum[r] += p;
      }
#pragma unroll
    for (int d = 1; d < 16; d <<= 1)
#pragma unroll
      for (int r = 0; r < 4; ++r) sum[r] += __shfl_xor(sum[r], d);
    f32x4 inv;
#pragma unroll
    for (int r = 0; r < 4; ++r) inv[r] = 1.0f / sum[r];
#pragma unroll
    for (int nt = 0; nt < 8; ++nt)
#pragma unroll
      for (int r = 0; r < 4; ++r)
        p_lds[w * 32 + mt * 16 + 4 * lg + r][nt * 16 + lr] = f2bf(s[mt][nt][r] * inv[r]);
  }
  // own-row reads in stage 4 -> no barrier

  // stage 4: prealign = P @ query_e[b] (K = 128) -> doc_out cols 300:600 f32
  const u16* qtp = qeT + (long)b * QETN * NQ;
  bf16x8 pa[2][4];
#pragma unroll
  for (int mt = 0; mt < 2; ++mt)
#pragma unroll
    for (int ksi = 0; ksi < 4; ++ksi)
      pa[mt][ksi] = *(const bf16x8*)&p_lds[w * 32 + mt * 16 + lr][ksi * 32 + 8 * lg];
#pragma unroll 2
  for (int nt = 0; nt < 19; ++nt) {
    f32x4 acc0 = {}, acc1 = {};
#pragma unroll
    for (int ksi = 0; ksi < 4; ++ksi) {
      bf16x8 bb = *(const bf16x8*)(qtp + (long)(nt * 16 + lr) * NQ + ksi * 32 + 8 * lg);
      acc0 = MFMA16(pa[0][ksi], bb, acc0);
      acc1 = MFMA16(pa[1][ksi], bb, acc1);
    }
    int col = nt * 16 + lr;
    if (col < NE) {
#pragma unroll
      for (int r = 0; r < 4; ++r) {
        long rl0 = blkrow + w * 32 + 4 * lg + r;
        doc_out[rl0 * DOC_W + 300 + col] = acc0[r];
        doc_out[(rl0 + 16) * DOC_W + 300 + col] = acc1[r];
      }
    }
  }
}

extern "C" void kernel_launch(void* const* d_in, const int* in_sizes, int n_in,
                              void* d_out, int out_size, void* d_ws, size_t ws_size,
                              hipStream_t stream) {
  // Size-based dispatch (R3/R4: identical to dict order; kept for robustness).
  const int *query_tok = nullptr, *doc_tok = nullptr, *doc_pos = nullptr, *doc_ner = nullptr;
  const float *doc_fea = nullptr, *word_emb = nullptr, *proj_w = nullptr,
              *proj_b = nullptr, *pos_emb = nullptr, *ner_emb = nullptr;
  int n65536 = 0;
  for (int i = 0; i < n_in; ++i) {
    switch (in_sizes[i]) {
      case 15000000: word_emb  = (const float*)d_in[i]; break;  // 50000*300
      case 262144:   doc_fea   = (const float*)d_in[i]; break;  // 64*1024*4
      case 76800:    proj_w    = (const float*)d_in[i]; break;  // 300*256
      case 8192:     query_tok = (const int*)d_in[i];   break;  // 64*128
      case 256:      proj_b    = (const float*)d_in[i]; break;
      case 672:      pos_emb   = (const float*)d_in[i]; break;  // 56*12
      case 152:      ner_emb   = (const float*)d_in[i]; break;  // 19*8
      case 65536:                                               // 64*1024 ints
        if (n65536 == 0)      doc_tok = (const int*)d_in[i];
        else if (n65536 == 1) doc_pos = (const int*)d_in[i];
        else                  doc_ner = (const int*)d_in[i];
        ++n65536; break;
      default: break;
    }
  }

  float* out = (float*)d_out;
  float* q_out   = out;                         // [B*Q][300] f32
  float* doc_out = out + (size_t)NB * NQ * NE;  // [B*D][624] f32

  char* ws = (char*)d_ws;
  u16* Wt   = (u16*)ws; ws += (size_t)NH * KP * 2;            // 160 KB
  u16* qP   = (u16*)ws; ws += (size_t)NB * NQ * NH * 2;       // 4 MB
  u16* qeT  = (u16*)ws; ws += (size_t)NB * QETN * NQ * 2;     // 4.75 MB
  u16* embB = (u16*)ws; ws += ((size_t)50000 * EBW + 64) * 2; // 30.4 MB (+pad)

  k_pre<<<dim3(5031), dim3(1024), 0, stream>>>(
      proj_w, Wt, query_tok, word_emb, q_out, qeT,
      doc_ner, doc_pos, doc_fea, ner_emb, pos_emb, doc_out, proj_b, qP, embB);
  k_fused<<<dim3(512), dim3(256), 0, stream>>>(
      doc_tok, embB, doc_out, Wt, proj_b, qP, qeT);
}